// Round 1
// baseline (33.605 us; speedup 1.0000x reference)
//
#include <hip/hip_runtime.h>

// DiagonalSSM kernel: out[d,h,l] = 2*Re( sum_n sc[d,h,n] * exp(delta_a[h,n]*l) )
// H=1024 channels, N=32 modes, L=2048 timesteps, D=2 directions.

#define H_DIM 1024
#define N_DIM 32
#define L_DIM 2048

__global__ __launch_bounds__(256) void DiagonalSSMKernel_18769007084374_kernel(
    const float* __restrict__ log_dt,
    const float* __restrict__ log_a_real,
    const float* __restrict__ a_imag,
    const float* __restrict__ coeffs,
    float* __restrict__ out)
{
    __shared__ float s_ar[N_DIM], s_ai[N_DIM];
    __shared__ float s_c0r[N_DIM], s_c0i[N_DIM], s_c1r[N_DIM], s_c1i[N_DIM];

    const int h = blockIdx.x;
    const int tid = threadIdx.x;

    if (tid < N_DIM) {
        const int n = tid;
        const float dt  = __expf(log_dt[h]);
        const float arl = -__expf(log_a_real[h * N_DIM + n]);   // Re(a) = -exp(log_a_real)
        const float aim = a_imag[h * N_DIM + n];                // Im(a)
        const float dar = arl * dt;                             // Re(delta_a)
        const float dai = aim * dt;                             // Im(delta_a)

        // (exp(delta_a) - 1) / a   -- complex
        const float er = __expf(dar);
        float si, co;
        __sincosf(dai, &si, &co);
        const float num_r = er * co - 1.0f;
        const float num_i = er * si;
        const float inv_den = 1.0f / (arl * arl + aim * aim);   // 1/|a|^2  (n=0: a=-0.5, fine)
        const float f_r = (num_r * arl + num_i * aim) * inv_den;
        const float f_i = (num_i * arl - num_r * aim) * inv_den;

        // scaled_coeffs = c * f, with the final factor 2 folded in
        {
            const float cr = coeffs[((0 * H_DIM + h) * N_DIM + n) * 2 + 0];
            const float ci = coeffs[((0 * H_DIM + h) * N_DIM + n) * 2 + 1];
            s_c0r[n] = 2.0f * (cr * f_r - ci * f_i);
            s_c0i[n] = 2.0f * (cr * f_i + ci * f_r);
        }
        {
            const float cr = coeffs[((1 * H_DIM + h) * N_DIM + n) * 2 + 0];
            const float ci = coeffs[((1 * H_DIM + h) * N_DIM + n) * 2 + 1];
            s_c1r[n] = 2.0f * (cr * f_r - ci * f_i);
            s_c1i[n] = 2.0f * (cr * f_i + ci * f_r);
        }
        s_ar[n] = dar;
        s_ai[n] = dai;
    }
    __syncthreads();

    const int l = blockIdx.y * 256 + tid;
    const float lf = (float)l;
    float acc0 = 0.0f, acc1 = 0.0f;

    #pragma unroll
    for (int n = 0; n < N_DIM; ++n) {
        const float w = __expf(s_ar[n] * lf);     // amplitude envelope
        float si, co;
        __sincosf(s_ai[n] * lf, &si, &co);        // phase
        const float wc = w * co;
        const float ws = w * si;
        // Re((cr + i*ci) * (wc + i*ws)) = cr*wc - ci*ws
        acc0 = fmaf(s_c0r[n],  wc, acc0);
        acc0 = fmaf(-s_c0i[n], ws, acc0);
        acc1 = fmaf(s_c1r[n],  wc, acc1);
        acc1 = fmaf(-s_c1i[n], ws, acc1);
    }

    out[(size_t)h * L_DIM + l] = acc0;
    out[(size_t)H_DIM * L_DIM + (size_t)h * L_DIM + l] = acc1;
}

extern "C" void kernel_launch(void* const* d_in, const int* in_sizes, int n_in,
                              void* d_out, int out_size, void* d_ws, size_t ws_size,
                              hipStream_t stream) {
    const float* log_dt     = (const float*)d_in[0];
    const float* log_a_real = (const float*)d_in[1];
    const float* a_imag     = (const float*)d_in[2];
    const float* coeffs     = (const float*)d_in[3];
    float* out = (float*)d_out;

    dim3 grid(H_DIM, L_DIM / 256);  // (1024, 8) blocks
    DiagonalSSMKernel_18769007084374_kernel<<<grid, 256, 0, stream>>>(
        log_dt, log_a_real, a_imag, coeffs, out);
}

// Round 2
// 21.783 us; speedup vs baseline: 1.5427x; 1.5427x over previous
//
#include <hip/hip_runtime.h>

// DiagonalSSM: out[d,h,l] = 2*Re( sum_n sc[d,h,n] * exp(delta_a[h,n]*l) )
// H=1024, N=32, L=2048, D=2.
// Strategy: per block = one h. 256 threads = 2 directions x 128 lane-offsets.
// Each thread owns l in {l0, l0+128, ...} (16 steps) and advances 32 complex
// states s[n] by q128[n] = exp(delta_a*128) per step (4 FMA per point-mode)
// instead of per-point exp/sincos.

#define H_DIM 1024
#define N_DIM 32
#define L_DIM 2048
#define STRIDE 128
#define ITERS (L_DIM / STRIDE)   // 16

__global__ __launch_bounds__(256) void DiagonalSSMKernel_18769007084374_kernel(
    const float* __restrict__ log_dt,
    const float* __restrict__ log_a_real,
    const float* __restrict__ a_imag,
    const float* __restrict__ coeffs,
    float* __restrict__ out)
{
    __shared__ float s_dar[N_DIM], s_dai[N_DIM];          // delta_a
    __shared__ float s_qr[N_DIM], s_qi[N_DIM];            // q128 = exp(delta_a*128)
    __shared__ float s_scr[2][N_DIM], s_sci[2][N_DIM];    // 2*c*(exp(da)-1)/a

    const int h = blockIdx.x;
    const int tid = threadIdx.x;

    if (tid < N_DIM) {
        const int n = tid;
        const float dt  = __expf(log_dt[h]);
        const float arl = -__expf(log_a_real[h * N_DIM + n]);   // Re(a)
        const float aim = a_imag[h * N_DIM + n];                // Im(a)
        const float dar = arl * dt;
        const float dai = aim * dt;

        // f = (exp(delta_a) - 1) / a
        const float er = __expf(dar);
        float si1, co1;
        __sincosf(dai, &si1, &co1);
        const float num_r = er * co1 - 1.0f;
        const float num_i = er * si1;
        const float inv_den = 1.0f / (arl * arl + aim * aim);
        const float f_r = (num_r * arl + num_i * aim) * inv_den;
        const float f_i = (num_i * arl - num_r * aim) * inv_den;

        #pragma unroll
        for (int d = 0; d < 2; ++d) {
            const float cr = coeffs[((d * H_DIM + h) * N_DIM + n) * 2 + 0];
            const float ci = coeffs[((d * H_DIM + h) * N_DIM + n) * 2 + 1];
            s_scr[d][n] = 2.0f * (cr * f_r - ci * f_i);
            s_sci[d][n] = 2.0f * (cr * f_i + ci * f_r);
        }

        s_dar[n] = dar;
        s_dai[n] = dai;

        // q128 = exp(delta_a * STRIDE)
        const float wq = __expf(dar * (float)STRIDE);
        float sq, cq;
        __sincosf(dai * (float)STRIDE, &sq, &cq);
        s_qr[n] = wq * cq;
        s_qi[n] = wq * sq;
    }
    __syncthreads();

    const int d  = tid >> 7;      // direction
    const int l0 = tid & 127;     // lane offset within stride
    const float lf = (float)l0;

    float sr[N_DIM], si[N_DIM], qr[N_DIM], qi[N_DIM];

    #pragma unroll
    for (int n = 0; n < N_DIM; ++n) {
        // z0 = exp(delta_a * l0)
        const float w = __expf(s_dar[n] * lf);
        float sn, cn;
        __sincosf(s_dai[n] * lf, &sn, &cn);
        const float zr = w * cn;
        const float zi = w * sn;
        const float cr = s_scr[d][n], ci = s_sci[d][n];
        sr[n] = cr * zr - ci * zi;
        si[n] = cr * zi + ci * zr;
        qr[n] = s_qr[n];
        qi[n] = s_qi[n];
    }

    float* outp = out + (size_t)d * H_DIM * L_DIM + (size_t)h * L_DIM + l0;

    for (int it = 0; it < ITERS; ++it) {
        // acc = sum_n Re(s[n])  -- pairwise tree to shorten the dep chain
        float tmp[N_DIM];
        #pragma unroll
        for (int n = 0; n < N_DIM; ++n) tmp[n] = sr[n];
        #pragma unroll
        for (int off = N_DIM / 2; off >= 1; off >>= 1) {
            #pragma unroll
            for (int n = 0; n < off; ++n) tmp[n] += tmp[n + off];
        }
        outp[it * STRIDE] = tmp[0];

        if (it + 1 < ITERS) {
            #pragma unroll
            for (int n = 0; n < N_DIM; ++n) {
                const float nr = sr[n] * qr[n] - si[n] * qi[n];
                const float ni = sr[n] * qi[n] + si[n] * qr[n];
                sr[n] = nr;
                si[n] = ni;
            }
        }
    }
}

extern "C" void kernel_launch(void* const* d_in, const int* in_sizes, int n_in,
                              void* d_out, int out_size, void* d_ws, size_t ws_size,
                              hipStream_t stream) {
    const float* log_dt     = (const float*)d_in[0];
    const float* log_a_real = (const float*)d_in[1];
    const float* a_imag     = (const float*)d_in[2];
    const float* coeffs     = (const float*)d_in[3];
    float* out = (float*)d_out;

    DiagonalSSMKernel_18769007084374_kernel<<<dim3(H_DIM), 256, 0, stream>>>(
        log_dt, log_a_real, a_imag, coeffs, out);
}